// Round 1
// baseline (677.591 us; speedup 1.0000x reference)
//
#include <hip/hip_runtime.h>
#include <hip/hip_cooperative_groups.h>

namespace cg = cooperative_groups;

// Problem constants
#define NB 64
#define NP 500
#define NC 128
#define NH 256
#define EPS_BN 1e-5f

// Edge-list geometry: 64 batches x 8 j-tiles, cap 1024 edges/segment
#define SEGS 8
#define CAPE 1024

// ws layout (float/int words)
#define EDGE_OFF 0
#define EDGE_WORDS (NB * SEGS * CAPE)            // 524288
#define CNT_OFF (EDGE_OFF + EDGE_WORDS)          // 524288, 512 words
#define CT_OFF (CNT_OFF + 512)                   // c matrix, feature-major [256][64]
#define H1_OFF (CT_OFF + NH * NB)
#define H2_OFF (H1_OFF + NH * NB)

// Output layout: tc[64] | tsys[64] | l2_points[4096000] | correlation[8192]
#define OUT_PTS_OFF 128
#define OUT_CORR_OFF 4096128
#define TOTAL_F4 1024000  // 4,096,000 floats / 4

#define GRID 512
#define COPY_BLKS 768     // fallback path only

struct Params {
  const float *xyz, *pts, *l3, *temp;
  const float *w0, *b0, *g0, *be0;
  const float *w1, *b1, *g1, *be1;
  const float *w2, *b2, *g2, *be2;
  const float *w3, *b3, *g3, *be3;
  const float *w4, *b4;
  float *out, *ws;
};

// ---------------------------------------------------------------------------
// MLP layer: y = relu(BN(x @ W^T + bias)); BN over batch dim (64 = one wave).
// One block per output feature o; 4 waves split K. Activations feature-major.
// If w4 != null: atomicAdd w4[o]*h into tc[b] instead of storing.
// ---------------------------------------------------------------------------
__device__ __forceinline__ void mlp_layer(int o, int tid, const float* xT,
                                          const float* W, const float* bias,
                                          const float* g, const float* be,
                                          float* yT, const float* w4,
                                          float* tc, float* part) {
  const int b = tid & 63;
  const int w = tid >> 6;
  const float* wr = W + o * NH + w * 64;
  const float* xp = xT + (w * 64) * 64 + b;
  float acc = 0.f;
#pragma unroll
  for (int i = 0; i < 64; ++i) acc += xp[i * 64] * wr[i];
  part[w * 64 + b] = acc;
  __syncthreads();
  if (w == 0) {
    float t = part[b] + part[64 + b] + part[128 + b] + part[192 + b] + bias[o];
    float s1 = t;
    for (int off = 32; off; off >>= 1) s1 += __shfl_xor(s1, off);
    float m = s1 * (1.f / 64.f);
    float d = t - m;
    float s2 = d * d;
    for (int off = 32; off; off >>= 1) s2 += __shfl_xor(s2, off);
    float var = s2 * (1.f / 64.f);
    float h = g[o] * d * rsqrtf(var + EPS_BN) + be[o];
    h = fmaxf(h, 0.f);
    if (w4) {
      atomicAdd(&tc[b], w4[o] * h);
    } else {
      yT[o * 64 + b] = h;
    }
  }
}

// Copy chunk k (of 4) of l2_points -> out, done by blocks NH..GRID-1
__device__ __forceinline__ void copy_slice(const float4* src, float4* dst,
                                           int k, int blk, int tid) {
  const int end = (k + 1) * (TOTAL_F4 / 4);
  for (int idx = k * (TOTAL_F4 / 4) + (blk - NH) * 256 + tid; idx < end;
       idx += (GRID - NH) * 256)
    dst[idx] = src[idx];
}

// ---------------------------------------------------------------------------
// Fully fused cooperative kernel.
// Phase 1: pair scan (all 512 blocks: b=blk>>3, jt=blk&7) + misc (blk<64)
// Phase 2: correlation (b=blk>>3, 16-channel group = blk&7)
// Phase 3: 4 MLP layers on blocks 0..255; blocks 256..511 copy l2_points
//          in 4 chunks overlapped with the MLP windows.
// ---------------------------------------------------------------------------
__global__ __launch_bounds__(256, 2) void fused(Params p) {
  cg::grid_group grid = cg::this_grid();
  const int blk = blockIdx.x;
  const int tid = threadIdx.x;
  // union'd LDS: phase1 pt[500] float4 (8KB) | phase2 dT[500][20] (40KB)
  // | phase3 part[4][64]; tail 16 floats for wsum/corrp.
  __shared__ __align__(16) float smem[NP * 20 + 16];  // 40,064 B
  __shared__ int lcnt;

  // ---------------- phase 1: pair scan + per-batch misc ------------------
  {
    const int b = blk >> 3;
    const int jt = blk & 7;
    float4* pt = (float4*)smem;
    if (tid == 0) lcnt = 0;
    const float* xr = p.xyz + b * 1500;
    for (int idx = tid; idx < NP; idx += 256) {
      float x = xr[idx], y = xr[500 + idx], z = xr[1000 + idx];
      pt[idx] = make_float4(x, y, z, x * x + y * y + z * z);
    }
    __syncthreads();

    const int j0 = jt * 63;
    const int j1 = (j0 + 63 < NP) ? j0 + 63 : NP;
    const int i0 = tid;
    const int i1 = tid + 256;
    float4 p0 = pt[i0];
    float4 p1 = (i1 < NP) ? pt[i1] : make_float4(0.f, 0.f, 0.f, 0.f);
    int* eseg = (int*)p.ws + EDGE_OFF + (b * SEGS + jt) * CAPE;

    for (int j = j0; j < j1; ++j) {
      float4 q = pt[j];  // wave-uniform -> LDS broadcast
      if (i0 < j) {
        float sq = p0.w + q.w - 2.f * (p0.x * q.x + p0.y * q.y + p0.z * q.z);
        float d = sqrtf(fabsf(sq));
        if (d > 0.19f && d < 0.21f) {
          int e = atomicAdd(&lcnt, 1);
          if (e < CAPE) eseg[e] = (i0 << 16) | j;
        }
      }
      if (i1 < j) {
        float sq = p1.w + q.w - 2.f * (p1.x * q.x + p1.y * q.y + p1.z * q.z);
        float d = sqrtf(fabsf(sq));
        if (d > 0.19f && d < 0.21f) {
          int e = atomicAdd(&lcnt, 1);
          if (e < CAPE) eseg[e] = (i1 << 16) | j;
        }
      }
    }
    __syncthreads();
    if (tid == 0) {
      int c = lcnt < CAPE ? lcnt : CAPE;
      ((int*)p.ws)[CNT_OFF + b * SEGS + jt] = c;
    }
  }
  if (blk < NB) {  // misc: tsys, sa4 rows of cT, tc bias init
    const int b = blk;
    float sum = 0.f;
    for (int i = tid; i < NP; i += 256) sum += p.temp[b * NP + i];
    for (int off = 32; off; off >>= 1) sum += __shfl_xor(sum, off);
    float* wsum = smem + NP * 20;
    if ((tid & 63) == 0) wsum[tid >> 6] = sum;
    __syncthreads();
    if (tid == 0)
      p.out[64 + b] = (wsum[0] + wsum[1] + wsum[2] + wsum[3]) * (1.f / 500.f);
    if (tid < NC) p.ws[CT_OFF + (NC + tid) * 64 + b] = p.l3[b * NC + tid];
    if (tid == 0) p.out[b] = p.b4[0];  // tc starts at bias
  }
  __threadfence();
  grid.sync();

  // ---------------- phase 2: correlation --------------------------------
  {
    const int b = blk >> 3;
    const int c0 = (blk & 7) * 16;
    float* dT = smem;                 // [j][c], 16 channels, stride 20
    float* corrp = smem + NP * 20;    // 16 partial sums
    if (tid < 16) corrp[tid] = 0.f;

    const float4* in4 = (const float4*)(p.pts + (size_t)b * 64000 + c0 * 500);
    for (int idx = tid; idx < 2000; idx += 256) {
      float4 v = in4[idx];
      int c = idx / 125;
      int j = (idx - c * 125) * 4;
      dT[(j + 0) * 20 + c] = v.x;
      dT[(j + 1) * 20 + c] = v.y;
      dT[(j + 2) * 20 + c] = v.z;
      dT[(j + 3) * 20 + c] = v.w;
    }
    __syncthreads();

    const int quad = tid & 3;
    const int slot = tid >> 2;
    float4 acc = make_float4(0.f, 0.f, 0.f, 0.f);
    const int* cnts = (const int*)p.ws + CNT_OFF + b * SEGS;
    int Etot = 0;
    for (int seg = 0; seg < SEGS; ++seg) {
      int E = cnts[seg];
      Etot += E;
      const int* eseg = (const int*)p.ws + EDGE_OFF + (b * SEGS + seg) * CAPE;
      for (int e = slot; e < E; e += 64) {
        int ij = eseg[e];
        int i = ij >> 16, j = ij & 0xffff;
        const float4 a = *(const float4*)(dT + i * 20 + quad * 4);
        const float4 c4 = *(const float4*)(dT + j * 20 + quad * 4);
        acc.x += a.x * c4.x;
        acc.y += a.y * c4.y;
        acc.z += a.z * c4.z;
        acc.w += a.w * c4.w;
      }
    }
    for (int off = 4; off < 64; off <<= 1) {
      acc.x += __shfl_xor(acc.x, off);
      acc.y += __shfl_xor(acc.y, off);
      acc.z += __shfl_xor(acc.z, off);
      acc.w += __shfl_xor(acc.w, off);
    }
    if ((tid & 63) < 4) {
      atomicAdd(&corrp[quad * 4 + 0], acc.x);
      atomicAdd(&corrp[quad * 4 + 1], acc.y);
      atomicAdd(&corrp[quad * 4 + 2], acc.z);
      atomicAdd(&corrp[quad * 4 + 3], acc.w);
    }
    __syncthreads();
    if (tid < 16) {
      float denom = fmaxf(2.f * (float)Etot, 1.f);  // ordered count = 2E
      float v = 2.f * corrp[tid] / denom;           // ordered sum = 2*upper
      p.out[OUT_CORR_OFF + b * NC + c0 + tid] = v;
      p.ws[CT_OFF + (c0 + tid) * 64 + b] = v;
    }
  }
  __threadfence();
  grid.sync();

  // ---------------- phase 3: MLP (blk<256) || copy (blk>=256) -----------
  {
    float* cT = p.ws + CT_OFF;
    float* hA = p.ws + H1_OFF;
    float* hB = p.ws + H2_OFF;
    float* part = smem;  // dT region is dead now
    const float4* src = (const float4*)p.pts;
    float4* dst = (float4*)(p.out + OUT_PTS_OFF);

    if (blk < NH)
      mlp_layer(blk, tid, cT, p.w0, p.b0, p.g0, p.be0, hA, nullptr, nullptr, part);
    else
      copy_slice(src, dst, 0, blk, tid);
    __threadfence();
    grid.sync();

    if (blk < NH)
      mlp_layer(blk, tid, hA, p.w1, p.b1, p.g1, p.be1, hB, nullptr, nullptr, part);
    else
      copy_slice(src, dst, 1, blk, tid);
    __threadfence();
    grid.sync();

    if (blk < NH)
      mlp_layer(blk, tid, hB, p.w2, p.b2, p.g2, p.be2, hA, nullptr, nullptr, part);
    else
      copy_slice(src, dst, 2, blk, tid);
    __threadfence();
    grid.sync();

    if (blk < NH)
      mlp_layer(blk, tid, hA, p.w3, p.b3, p.g3, p.be3, nullptr, p.w4, p.out, part);
    else
      copy_slice(src, dst, 3, blk, tid);
  }
}

// ===========================================================================
// Fallback path: the previous, harness-verified 6-kernel pipeline (used only
// if the cooperative launch is rejected, e.g. capture/occupancy refusal).
// ===========================================================================
__global__ __launch_bounds__(256) void k1_scan_misc_copy(
    const float* __restrict__ xyz, const float* __restrict__ temp,
    const float* __restrict__ l3, const float* __restrict__ b4,
    const float* __restrict__ pts, float* __restrict__ out,
    float* __restrict__ ws) {
  const int blk = blockIdx.x;
  const int tid = threadIdx.x;

  if (blk < 512) {
    const int b = blk >> 3;
    const int jt = blk & 7;
    __shared__ float4 pt[NP];
    __shared__ int lcnt;
    if (tid == 0) lcnt = 0;
    const float* xr = xyz + b * 1500;
    for (int idx = tid; idx < NP; idx += 256) {
      float x = xr[idx], y = xr[500 + idx], z = xr[1000 + idx];
      pt[idx] = make_float4(x, y, z, x * x + y * y + z * z);
    }
    __syncthreads();
    const int j0 = jt * 63;
    const int j1 = (j0 + 63 < NP) ? j0 + 63 : NP;
    const int i0 = tid, i1 = tid + 256;
    float4 p0 = pt[i0];
    float4 p1 = (i1 < NP) ? pt[i1] : make_float4(0.f, 0.f, 0.f, 0.f);
    int* eseg = (int*)ws + EDGE_OFF + (b * SEGS + jt) * CAPE;
    for (int j = j0; j < j1; ++j) {
      float4 q = pt[j];
      if (i0 < j) {
        float sq = p0.w + q.w - 2.f * (p0.x * q.x + p0.y * q.y + p0.z * q.z);
        float d = sqrtf(fabsf(sq));
        if (d > 0.19f && d < 0.21f) {
          int e = atomicAdd(&lcnt, 1);
          if (e < CAPE) eseg[e] = (i0 << 16) | j;
        }
      }
      if (i1 < j) {
        float sq = p1.w + q.w - 2.f * (p1.x * q.x + p1.y * q.y + p1.z * q.z);
        float d = sqrtf(fabsf(sq));
        if (d > 0.19f && d < 0.21f) {
          int e = atomicAdd(&lcnt, 1);
          if (e < CAPE) eseg[e] = (i1 << 16) | j;
        }
      }
    }
    __syncthreads();
    if (tid == 0) {
      int c = lcnt < CAPE ? lcnt : CAPE;
      ((int*)ws)[CNT_OFF + b * SEGS + jt] = c;
    }
  } else if (blk < 576) {
    const int b = blk - 512;
    float sum = 0.f;
    for (int i = tid; i < NP; i += 256) sum += temp[b * NP + i];
    for (int off = 32; off; off >>= 1) sum += __shfl_xor(sum, off);
    __shared__ float wsum[4];
    if ((tid & 63) == 0) wsum[tid >> 6] = sum;
    __syncthreads();
    if (tid == 0)
      out[64 + b] = (wsum[0] + wsum[1] + wsum[2] + wsum[3]) * (1.f / 500.f);
    if (tid < 128) ws[CT_OFF + (128 + tid) * 64 + b] = l3[b * NC + tid];
    if (tid == 0) out[b] = b4[0];
  } else {
    const int cb = blk - 576;
    const float4* src = (const float4*)pts;
    float4* dst = (float4*)(out + OUT_PTS_OFF);
    for (int idx = cb * 256 + tid; idx < TOTAL_F4 / 2; idx += COPY_BLKS * 256)
      dst[idx] = src[idx];
  }
}

__global__ __launch_bounds__(256) void k2_corr_copy(
    const float* __restrict__ data, float* __restrict__ out,
    float* __restrict__ ws) {
  const int blk = blockIdx.x;
  const int tid = threadIdx.x;

  if (blk < 512) {
    const int b = blk >> 3;
    const int c0 = (blk & 7) * 16;
    __shared__ float dT[NP * 20];
    __shared__ float corrp[16];
    if (tid < 16) corrp[tid] = 0.f;
    const float4* in4 = (const float4*)(data + (size_t)b * 64000 + c0 * 500);
    for (int idx = tid; idx < 2000; idx += 256) {
      float4 v = in4[idx];
      int c = idx / 125;
      int j = (idx - c * 125) * 4;
      dT[(j + 0) * 20 + c] = v.x;
      dT[(j + 1) * 20 + c] = v.y;
      dT[(j + 2) * 20 + c] = v.z;
      dT[(j + 3) * 20 + c] = v.w;
    }
    __syncthreads();
    const int quad = tid & 3;
    const int slot = tid >> 2;
    float4 acc = make_float4(0.f, 0.f, 0.f, 0.f);
    const int* cnts = (const int*)ws + CNT_OFF + b * SEGS;
    int Etot = 0;
    for (int seg = 0; seg < SEGS; ++seg) {
      int E = cnts[seg];
      Etot += E;
      const int* eseg = (const int*)ws + EDGE_OFF + (b * SEGS + seg) * CAPE;
      for (int e = slot; e < E; e += 64) {
        int ij = eseg[e];
        int i = ij >> 16, j = ij & 0xffff;
        const float4 a = *(const float4*)(dT + i * 20 + quad * 4);
        const float4 c4 = *(const float4*)(dT + j * 20 + quad * 4);
        acc.x += a.x * c4.x;
        acc.y += a.y * c4.y;
        acc.z += a.z * c4.z;
        acc.w += a.w * c4.w;
      }
    }
    for (int off = 4; off < 64; off <<= 1) {
      acc.x += __shfl_xor(acc.x, off);
      acc.y += __shfl_xor(acc.y, off);
      acc.z += __shfl_xor(acc.z, off);
      acc.w += __shfl_xor(acc.w, off);
    }
    if ((tid & 63) < 4) {
      atomicAdd(&corrp[quad * 4 + 0], acc.x);
      atomicAdd(&corrp[quad * 4 + 1], acc.y);
      atomicAdd(&corrp[quad * 4 + 2], acc.z);
      atomicAdd(&corrp[quad * 4 + 3], acc.w);
    }
    __syncthreads();
    if (tid < 16) {
      float denom = fmaxf(2.f * (float)Etot, 1.f);
      float v = 2.f * corrp[tid] / denom;
      out[OUT_CORR_OFF + b * NC + c0 + tid] = v;
      ws[CT_OFF + (c0 + tid) * 64 + b] = v;
    }
  } else {
    const int cb = blk - 512;
    const float4* src = (const float4*)data;
    float4* dst = (float4*)(out + OUT_PTS_OFF);
    for (int idx = TOTAL_F4 / 2 + cb * 256 + tid; idx < TOTAL_F4;
         idx += COPY_BLKS * 256)
      dst[idx] = src[idx];
  }
}

__global__ __launch_bounds__(256) void layer_k(
    const float* __restrict__ xT, const float* __restrict__ W,
    const float* __restrict__ bias, const float* __restrict__ g,
    const float* __restrict__ be, float* __restrict__ yT,
    const float* __restrict__ w4, float* __restrict__ tc) {
  __shared__ float part[4 * 64];
  mlp_layer(blockIdx.x, threadIdx.x, xT, W, bias, g, be, yT, w4, tc, part);
}

extern "C" void kernel_launch(void* const* d_in, const int* in_sizes, int n_in,
                              void* d_out, int out_size, void* d_ws,
                              size_t ws_size, hipStream_t stream) {
  Params p;
  p.xyz = (const float*)d_in[0];
  p.pts = (const float*)d_in[1];
  p.l3 = (const float*)d_in[2];
  p.temp = (const float*)d_in[3];
  p.w0 = (const float*)d_in[4];
  p.b0 = (const float*)d_in[5];
  p.g0 = (const float*)d_in[6];
  p.be0 = (const float*)d_in[7];
  p.w1 = (const float*)d_in[8];
  p.b1 = (const float*)d_in[9];
  p.g1 = (const float*)d_in[10];
  p.be1 = (const float*)d_in[11];
  p.w2 = (const float*)d_in[12];
  p.b2 = (const float*)d_in[13];
  p.g2 = (const float*)d_in[14];
  p.be2 = (const float*)d_in[15];
  p.w3 = (const float*)d_in[16];
  p.b3 = (const float*)d_in[17];
  p.g3 = (const float*)d_in[18];
  p.be3 = (const float*)d_in[19];
  p.w4 = (const float*)d_in[20];
  p.b4 = (const float*)d_in[21];
  p.out = (float*)d_out;
  p.ws = (float*)d_ws;

  void* args[] = {(void*)&p};
  hipError_t err = hipLaunchCooperativeKernel((const void*)fused, dim3(GRID),
                                              dim3(256), args, 0, stream);
  if (err != hipSuccess) {
    // Fallback: previous verified 6-kernel pipeline
    float* out = p.out;
    float* ws = p.ws;
    float* cT = ws + CT_OFF;
    float* hA = ws + H1_OFF;
    float* hB = ws + H2_OFF;
    k1_scan_misc_copy<<<576 + COPY_BLKS, 256, 0, stream>>>(
        p.xyz, p.temp, p.l3, p.b4, p.pts, out, ws);
    k2_corr_copy<<<512 + COPY_BLKS, 256, 0, stream>>>(p.pts, out, ws);
    layer_k<<<256, 256, 0, stream>>>(cT, p.w0, p.b0, p.g0, p.be0, hA, nullptr,
                                     nullptr);
    layer_k<<<256, 256, 0, stream>>>(hA, p.w1, p.b1, p.g1, p.be1, hB, nullptr,
                                     nullptr);
    layer_k<<<256, 256, 0, stream>>>(hB, p.w2, p.b2, p.g2, p.be2, hA, nullptr,
                                     nullptr);
    layer_k<<<256, 256, 0, stream>>>(hA, p.w3, p.b3, p.g3, p.be3, nullptr,
                                     p.w4, out);
  }
}

// Round 2
// 260.609 us; speedup vs baseline: 2.6000x; 2.6000x over previous
//
#include <hip/hip_runtime.h>

// Problem constants
#define NB 64
#define NP 500
#define NC 128
#define NH 256
#define EPS_BN 1e-5f

// ws layout (float words): activations only — no edge lists anymore
#define CT_OFF 0                       // c matrix, feature-major [256][64]
#define H1_OFF (CT_OFF + NH * NB)
#define H2_OFF (H1_OFF + NH * NB)

// Output layout: tc[64] | tsys[64] | l2_points[4096000] | correlation[8192]
#define OUT_PTS_OFF 128
#define OUT_CORR_OFF 4096128
#define TOTAL_F4 1024000  // 4,096,000 floats / 4

// kA grid: 512 scan+corr | 64 misc | 1024 copy
#define SCAN_BLKS 512
#define MISC_END 576
#define KA_GRID 1600
#define CPY_BLKS (KA_GRID - MISC_END)

// ---------------------------------------------------------------------------
// K_A: fused pair-scan + correlation (self-contained per block), misc, copy.
//
// Block (b, cg): stages pt[500] (xyz + |p|^2, 8KB) and dT[500][20] (16
// channels of l2_points, transposed, 40KB). Scans the full i<j triangle
// (each thread owns i=tid and i=tid+256; j-loop 1..499 with LDS-broadcast
// q=pt[j]). On a band hit, accumulates 16 channel products into registers
// and counts the edge. End: wave shuffle-reduce + LDS combine, write
// correlation to out and to cT for the MLP. Identical math to the verified
// edge-list version (upper sum doubled over ordered count 2E), but exact
// (no CAPE cap) and with zero inter-kernel dependency.
// ---------------------------------------------------------------------------
__global__ __launch_bounds__(256) void kA(
    const float* __restrict__ xyz,    // [B,3,N]
    const float* __restrict__ pts,    // [B,C,N] l2_points
    const float* __restrict__ l3,     // [B,C]
    const float* __restrict__ temp,   // [B,1,N]
    const float* __restrict__ b4,     // [1] fc_lt4_b
    float* __restrict__ out,
    float* __restrict__ ws) {
  const int blk = blockIdx.x;
  const int tid = threadIdx.x;

  // Static LDS shared by all branches: dT[500][20] + 68-word tail + pt[500]
  __shared__ __align__(16) float smem[NP * 20 + 68];  // 40,272 B
  __shared__ __align__(16) float4 pt[NP];             //  8,000 B

  if (blk < SCAN_BLKS) {
    const int b = blk >> 3;
    const int c0 = (blk & 7) * 16;
    float* dT = smem;
    float* partials = smem + NP * 20;  // [4][17]: 16 channel sums + count

    // stage pt (same expressions as the verified scan)
    const float* xr = xyz + b * 1500;
    for (int idx = tid; idx < NP; idx += 256) {
      float x = xr[idx], y = xr[500 + idx], z = xr[1000 + idx];
      pt[idx] = make_float4(x, y, z, x * x + y * y + z * z);
    }
    // stage dT: 16 contiguous channel rows, transposed (verbatim from k2)
    const float4* in4 = (const float4*)(pts + (size_t)b * 64000 + c0 * 500);
    for (int idx = tid; idx < 2000; idx += 256) {
      float4 v = in4[idx];
      int c = idx / 125;
      int j = (idx - c * 125) * 4;
      dT[(j + 0) * 20 + c] = v.x;
      dT[(j + 1) * 20 + c] = v.y;
      dT[(j + 2) * 20 + c] = v.z;
      dT[(j + 3) * 20 + c] = v.w;
    }
    __syncthreads();

    const int i0 = tid;
    const int i1 = tid + 256;
    float4 p0 = pt[i0];
    float4 p1 = (i1 < NP) ? pt[i1] : make_float4(0.f, 0.f, 0.f, 0.f);

    float acc[16];
#pragma unroll
    for (int c = 0; c < 16; ++c) acc[c] = 0.f;
    int ecnt = 0;

    for (int j = 1; j < NP; ++j) {
      float4 q = pt[j];  // wave-uniform -> LDS broadcast
      if (i0 < j) {
        float dot = p0.x * q.x + p0.y * q.y + p0.z * q.z;
        float sq = p0.w + q.w - 2.f * dot;
        float d = sqrtf(fabsf(sq));
        if (d > 0.19f && d < 0.21f) {
          ++ecnt;
          const float4* ai = (const float4*)(dT + i0 * 20);
          const float4* aj = (const float4*)(dT + j * 20);
#pragma unroll
          for (int qd = 0; qd < 4; ++qd) {
            float4 a = ai[qd], bb = aj[qd];
            acc[4 * qd + 0] += a.x * bb.x;
            acc[4 * qd + 1] += a.y * bb.y;
            acc[4 * qd + 2] += a.z * bb.z;
            acc[4 * qd + 3] += a.w * bb.w;
          }
        }
      }
      if (i1 < j) {  // implies i1 < 500
        float dot = p1.x * q.x + p1.y * q.y + p1.z * q.z;
        float sq = p1.w + q.w - 2.f * dot;
        float d = sqrtf(fabsf(sq));
        if (d > 0.19f && d < 0.21f) {
          ++ecnt;
          const float4* ai = (const float4*)(dT + i1 * 20);
          const float4* aj = (const float4*)(dT + j * 20);
#pragma unroll
          for (int qd = 0; qd < 4; ++qd) {
            float4 a = ai[qd], bb = aj[qd];
            acc[4 * qd + 0] += a.x * bb.x;
            acc[4 * qd + 1] += a.y * bb.y;
            acc[4 * qd + 2] += a.z * bb.z;
            acc[4 * qd + 3] += a.w * bb.w;
          }
        }
      }
    }

    // reduce 16 sums + count across the 64-lane wave
#pragma unroll
    for (int c = 0; c < 16; ++c)
      for (int off = 32; off; off >>= 1) acc[c] += __shfl_xor(acc[c], off);
    float ec = (float)ecnt;
    for (int off = 32; off; off >>= 1) ec += __shfl_xor(ec, off);

    const int w = tid >> 6;
    if ((tid & 63) == 0) {
#pragma unroll
      for (int c = 0; c < 16; ++c) partials[w * 17 + c] = acc[c];
      partials[w * 17 + 16] = ec;
    }
    __syncthreads();
    if (tid < 16) {
      float S = partials[tid] + partials[17 + tid] + partials[34 + tid] +
                partials[51 + tid];
      float E = partials[16] + partials[33] + partials[50] + partials[67];
      // mask symmetric: ordered count = 2E, ordered sum = 2 * upper sum
      float v = 2.f * S / fmaxf(2.f * E, 1.f);
      out[OUT_CORR_OFF + b * NC + c0 + tid] = v;
      ws[CT_OFF + (c0 + tid) * 64 + b] = v;
    }
  } else if (blk < MISC_END) {
    // misc per batch: tsys, cT sa4 rows, tc bias init
    const int b = blk - SCAN_BLKS;
    float sum = 0.f;
    for (int i = tid; i < NP; i += 256) sum += temp[b * NP + i];
    for (int off = 32; off; off >>= 1) sum += __shfl_xor(sum, off);
    float* wsum = smem;  // scan branch not active in this block
    if ((tid & 63) == 0) wsum[tid >> 6] = sum;
    __syncthreads();
    if (tid == 0)
      out[64 + b] = (wsum[0] + wsum[1] + wsum[2] + wsum[3]) * (1.f / 500.f);
    if (tid < NC) ws[CT_OFF + (NC + tid) * 64 + b] = l3[b * NC + tid];
    if (tid == 0) out[b] = b4[0];  // tc starts at bias; layer-lt1 atomicAdds
  } else {
    // copy all of l2_points -> out
    const int cb = blk - MISC_END;
    const float4* src = (const float4*)pts;
    float4* dst = (float4*)(out + OUT_PTS_OFF);
    for (int idx = cb * 256 + tid; idx < TOTAL_F4; idx += CPY_BLKS * 256)
      dst[idx] = src[idx];
  }
}

// ---------------------------------------------------------------------------
// Layer: y = relu(BN(x @ W^T + bias)); BN over batch dim (64 = one wave).
// Grid: 256 blocks (one output feature) x 256 threads (4 waves split K).
// Activations feature-major [256][64] for coalescing.
// If w4 != null: instead of storing, atomicAdd w4[o]*h into tc[b].
// (Verbatim from the 165 µs harness-verified baseline.)
// ---------------------------------------------------------------------------
__global__ __launch_bounds__(256) void layer_k(
    const float* __restrict__ xT, const float* __restrict__ W,
    const float* __restrict__ bias, const float* __restrict__ g,
    const float* __restrict__ be, float* __restrict__ yT,
    const float* __restrict__ w4, float* __restrict__ tc) {
  const int o = blockIdx.x;
  const int b = threadIdx.x & 63;
  const int w = threadIdx.x >> 6;
  const float* wr = W + o * NH + w * 64;
  const float* xp = xT + (w * 64) * 64 + b;
  float acc = 0.f;
#pragma unroll
  for (int i = 0; i < 64; ++i) acc += xp[i * 64] * wr[i];
  __shared__ float part[4][64];
  part[w][b] = acc;
  __syncthreads();
  if (w == 0) {
    float t = part[0][b] + part[1][b] + part[2][b] + part[3][b] + bias[o];
    float s1 = t;
    for (int off = 32; off; off >>= 1) s1 += __shfl_xor(s1, off);
    float m = s1 * (1.f / 64.f);
    float d = t - m;
    float s2 = d * d;
    for (int off = 32; off; off >>= 1) s2 += __shfl_xor(s2, off);
    float var = s2 * (1.f / 64.f);
    float h = g[o] * d * rsqrtf(var + EPS_BN) + be[o];
    h = fmaxf(h, 0.f);
    if (w4) {
      atomicAdd(&tc[b], w4[o] * h);
    } else {
      yT[o * 64 + b] = h;
    }
  }
}

extern "C" void kernel_launch(void* const* d_in, const int* in_sizes, int n_in,
                              void* d_out, int out_size, void* d_ws,
                              size_t ws_size, hipStream_t stream) {
  const float* xyz = (const float*)d_in[0];
  const float* pts = (const float*)d_in[1];
  const float* l3 = (const float*)d_in[2];
  const float* temp = (const float*)d_in[3];
  const float* w0 = (const float*)d_in[4];
  const float* b0 = (const float*)d_in[5];
  const float* g0 = (const float*)d_in[6];
  const float* be0 = (const float*)d_in[7];
  const float* w1 = (const float*)d_in[8];
  const float* b1 = (const float*)d_in[9];
  const float* g1 = (const float*)d_in[10];
  const float* be1 = (const float*)d_in[11];
  const float* w2 = (const float*)d_in[12];
  const float* b2 = (const float*)d_in[13];
  const float* g2 = (const float*)d_in[14];
  const float* be2 = (const float*)d_in[15];
  const float* w3 = (const float*)d_in[16];
  const float* b3 = (const float*)d_in[17];
  const float* g3 = (const float*)d_in[18];
  const float* be3 = (const float*)d_in[19];
  const float* w4 = (const float*)d_in[20];
  const float* b4 = (const float*)d_in[21];

  float* out = (float*)d_out;
  float* ws = (float*)d_ws;
  float* cT = ws + CT_OFF;
  float* hA = ws + H1_OFF;
  float* hB = ws + H2_OFF;

  kA<<<KA_GRID, 256, 0, stream>>>(xyz, pts, l3, temp, b4, out, ws);
  layer_k<<<256, 256, 0, stream>>>(cT, w0, b0, g0, be0, hA, nullptr, nullptr);
  layer_k<<<256, 256, 0, stream>>>(hA, w1, b1, g1, be1, hB, nullptr, nullptr);
  layer_k<<<256, 256, 0, stream>>>(hB, w2, b2, g2, be2, hA, nullptr, nullptr);
  layer_k<<<256, 256, 0, stream>>>(hA, w3, b3, g3, be3, nullptr, w4, out);
}